// Round 4
// baseline (143.047 us; speedup 1.0000x reference)
//
#include <hip/hip_runtime.h>

// Profile-HMM forward (log2-domain) + KLD, MI355X.
// v4: 128 threads (2 waves) per batch element; lane j owns ONE state k=j+1.
// Skewed schedule: at step s, global lane j computes column c = s - j.
// Wave 1 runs 4 steps behind wave 0; the k=63->64 seam goes through a
// 16-slot LDS ring with one __syncthreads() per 4-step group.

constexpr float LOG2E = 1.4426950408889634f;
constexpr float LN2   = 0.6931471805599453f;
constexpr float NEG2  = -100.0f * 1.4426950408889634f; // NEG in log2 units
constexpr float LQ2   = -2.0f;                         // log2(0.25)

// log2(1+e) on [0,1]: Taylor @ e=0.5, deg 5 (max err ~5e-4)
constexpr float K0 = 0.5849625007f, K1 = 0.9617966939f, K2 = -0.3205988980f,
                K3 = 0.1424883991f, K4 = -0.0712441995f, K5 = 0.0379969064f;
// log2(s) on [1,3] via v=s-2: Taylor @ s=2, deg 6 (max err ~3e-3)
constexpr float M0 = 1.0f, M1 = 0.7213475204f, M2 = -0.1803368801f,
                M3 = 0.0601122934f, M4 = -0.0225421100f, M5 = 0.0090168440f,
                M6 = -0.0037570184f;

__device__ __forceinline__ float exp2_hw(float x) {
    float r; asm("v_exp_f32 %0, %1" : "=v"(r) : "v"(x)); return r;
}
__device__ __forceinline__ float plog1p(float e) { // log2(1+e), e in [0,1]
    float u  = e - 0.5f;
    float u2 = u * u;
    float a  = fmaf(u, K1, K0);
    float b  = fmaf(u, K3, K2);
    float c  = fmaf(u, K5, K4);
    return fmaf(u2, fmaf(u2, c, b), a);
}
__device__ __forceinline__ float lae2(float x, float y) { // log2(2^x + 2^y)
    float m = fmaxf(x, y);
    float d = x - y;
    float e = exp2_hw(fminf(d, -d)); // 2^(-|d|)
    return m + plog1p(e);
}
__device__ __forceinline__ float lse3(float p, float q, float r) {
    float m = fmaxf(fmaxf(p, q), r); // v_max3
    float s = exp2_hw(p - m) + exp2_hw(q - m) + exp2_hw(r - m); // in [1,3]
    float v  = s - 2.0f;
    float v2 = v * v;
    float A  = fmaf(v, M1, M0);
    float B  = fmaf(v, M3, M2);
    float C  = fmaf(v, M5, M4);
    float CD = fmaf(v2, M6, C);
    return m + fmaf(v2, fmaf(v2, CD, B), A);
}

// One pipeline step for this lane.
// q* = neighbor (k-1) state at col c (neighbor computed it last step) -> feeds D.
// p* = neighbor state at col c-1 (saved from last step's q*)          -> feeds M.
// c* = own state at col c-1                                           -> feeds I.
#define STEP(JJ, FRESH, M00) do {                                              \
    const float qM_ = __int_as_float(__builtin_amdgcn_ds_bpermute(up4, __float_as_int(cM))); \
    const float qI_ = __int_as_float(__builtin_amdgcn_ds_bpermute(up4, __float_as_int(cI))); \
    const float qD_ = __int_as_float(__builtin_amdgcn_ds_bpermute(up4, __float_as_int(cD))); \
    const int   qT_ = __builtin_amdgcn_ds_bpermute(up4, tok);                  \
    float nI0_ = NEG2;                                                         \
    if (wid == 0) nI0_ = lae2(A0 + (M00), B0 + fI0);                           \
    const float nMp_ = lse3(rM2M + pM, rI2M + pI, rD2M + pD);                  \
    const float nI_  = lae2(oM2I + cM, oI2I + cI);                             \
    float qM = qM_, qI = qI_, qD = qD_; int qT = qT_;                          \
    if (seamr) { const float4 r_ = ring[(unsigned)(s0 + (JJ) - 1) & 15u];      \
                 qM = r_.x; qI = r_.y; qD = r_.z; qT = __float_as_int(r_.w); } \
    if (lane00) { qM = NEG2; qI = nI0_; qD = NEG2; qT = (FRESH); }             \
    tok = qT;                                                                  \
    const float e_ = (tok & 2) ? ((tok & 1) ? em.w : em.z)                     \
                               : ((tok & 1) ? em.y : em.x);                    \
    const float nM_ = nMp_ + e_;                                               \
    const float nD_ = lae2(rM2D + qM, rD2D + qD);                              \
    const int c_ = cb + (JJ);                                                  \
    const bool act_  = ((unsigned)(c_ - 1)) < 256u; /* 1 <= c <= 256 */        \
    const bool actD_ = ((unsigned)c_) < 257u;       /* 0 <= c <= 256 */        \
    cM = act_  ? nM_ : cM;                                                     \
    cI = act_  ? nI_ : cI;                                                     \
    cD = actD_ ? nD_ : cD;                                                     \
    pM = qM; pI = qI; pD = qD;                                                 \
    if (wid == 0) fI0 = nI0_;                                                  \
    if (seamw) ring[(unsigned)(s0 + (JJ)) & 15u] =                             \
                   make_float4(cM, cI, cD, __int_as_float(tok));               \
} while (0)

// transitions: (B, 129, 7)  M2M=0 M2I=1 M2D=2 I2M=3 I2I=4 D2M=5 D2D=6
// emissions:   (B, 128, 4);  tokens: (B, 256) int32 in [0,4)
__global__ __launch_bounds__(128) void phmm_fwd(const int* __restrict__ tokens,
                                                const float* __restrict__ trans,
                                                const float* __restrict__ emis,
                                                float* __restrict__ nll_out)
{
    const int b   = blockIdx.x;
    const int tid = threadIdx.x;
    const int wid = tid >> 6;   // wave id 0/1
    const int i   = tid & 63;   // lane within wave
    const int j   = tid;        // global lane; owns state k = j+1
    const int up4 = (i - 1) * 4;

    const float* ab = trans + (size_t)b * 903;
    // row j (feeds M-recurrence and D-recurrence of state k=j+1)
    const float rM2M = ab[j*7+0]*LOG2E, rI2M = ab[j*7+3]*LOG2E, rD2M = ab[j*7+5]*LOG2E;
    const float rM2D = ab[j*7+2]*LOG2E, rD2D = ab[j*7+6]*LOG2E;
    // row j+1 (feeds own I-recurrence; for lane 127 this is row 128 = final row)
    const float oM2I = ab[(j+1)*7+1]*LOG2E + LQ2, oI2I = ab[(j+1)*7+4]*LOG2E + LQ2;
    const float fM2M = ab[(j+1)*7+0]*LOG2E, fI2M = ab[(j+1)*7+3]*LOG2E,
                fD2M = ab[(j+1)*7+5]*LOG2E;
    // row 0 specials (k=0 insert-state recurrence; block-uniform scalar loads)
    const float A0 = ab[1]*LOG2E + LQ2, B0 = ab[4]*LOG2E + LQ2;

    float4 em = ((const float4*)(emis + (size_t)b * 512))[j];
    em.x *= LOG2E; em.y *= LOG2E; em.z *= LOG2E; em.w *= LOG2E;

    // token int4 per lane-in-wave; wave 1 loads the same (FRESH unused there)
    const int4 ts = ((const int4*)(tokens + (size_t)b * 256))[i];

    __shared__ float4 ring[16];
    if (tid < 16) ring[tid] = make_float4(NEG2, NEG2, NEG2, 0.0f);
    __syncthreads();

    const bool lane00 = (tid == 0);   // global lane 0 (k=1): neighbor is row 0
    const bool seamw  = (tid == 63);  // wave-0 boundary producer
    const bool seamr  = (tid == 64);  // wave-1 boundary consumer

    // State: own (fM,fI,fD) at column c-1 (log2 units)
    float cM = NEG2, cI = NEG2, cD = NEG2;
    if (lane00) cD = lae2(rM2D + 0.0f, rD2D + NEG2); // fD[0][1]
    float pM = lane00 ? 0.0f : NEG2;                 // fM[0][0] = 0
    float pI = NEG2, pD = NEG2;
    float fI0 = NEG2;                                // fI[0][c-1] (wave 0 only)
    int tok = 0;

    int s0 = 1 - 4 * wid;  // this wave's step at jj=0 (wave 1 lags 4 steps)
    int cb = s0 - j;       // own column at jj=0

    // groups n = 0..96: wave-0 steps 1..388, wave-1 steps -3..384 (needs 383)
    #pragma unroll 1
    for (int n = 0; n <= 96; ++n) {
        const int sel = n & 63;
        const int f0 = __builtin_amdgcn_readlane(ts.x, sel);
        const int f1 = __builtin_amdgcn_readlane(ts.y, sel);
        const int f2 = __builtin_amdgcn_readlane(ts.z, sel);
        const int f3 = __builtin_amdgcn_readlane(ts.w, sel);
        const float m00 = (n == 0) ? 0.0f : NEG2; // fM[0][0]=0 only at step 1
        STEP(0, f0, m00);
        STEP(1, f1, NEG2);
        STEP(2, f2, NEG2);
        STEP(3, f3, NEG2);
        __syncthreads();
        s0 += 4; cb += 4;
    }

    // lane 127 holds f*[256][128]; row j+1 = 128 supplies the final transitions
    const float fin = lse3(cM + fM2M, cI + fI2M, cD + fD2M);
    if (tid == 127) nll_out[b] = -fin * LN2;
}

__global__ __launch_bounds__(256) void phmm_finish(const float* __restrict__ nll,
                                                   const float* __restrict__ mus,
                                                   const float* __restrict__ logvars,
                                                   float* __restrict__ out)
{
    const int tid = threadIdx.x;
    float acc = 0.0f;
    for (int idx = tid; idx < 512; idx += 256) acc += nll[idx];
    for (int idx = tid; idx < 8192; idx += 256) {
        const float mu = mus[idx], lv = logvars[idx];
        acc -= 0.5f * (1.0f + lv - mu * mu - exp2_hw(lv * LOG2E));
    }
    #pragma unroll
    for (int off = 32; off >= 1; off >>= 1) acc += __shfl_down(acc, off);
    __shared__ float red[4];
    if ((tid & 63) == 0) red[tid >> 6] = acc;
    __syncthreads();
    if (tid == 0) out[0] = (red[0] + red[1] + red[2] + red[3]) * (1.0f / 512.0f);
}

extern "C" void kernel_launch(void* const* d_in, const int* in_sizes, int n_in,
                              void* d_out, int out_size, void* d_ws, size_t ws_size,
                              hipStream_t stream)
{
    const int*   tokens  = (const int*)d_in[0];   // (512, 256) int32
    const float* trans   = (const float*)d_in[1]; // (512, 129, 7) f32
    const float* emis    = (const float*)d_in[2]; // (512, 128, 4) f32
    const float* mus     = (const float*)d_in[3]; // (512, 16) f32
    const float* logvars = (const float*)d_in[4]; // (512, 16) f32
    float* nll = (float*)d_ws;                    // 512 floats scratch

    phmm_fwd<<<dim3(512), dim3(128), 0, stream>>>(tokens, trans, emis, nll);
    phmm_finish<<<dim3(1), dim3(256), 0, stream>>>(nll, mus, logvars, (float*)d_out);
}

// Round 5
// 113.018 us; speedup vs baseline: 1.2657x; 1.2657x over previous
//
#include <hip/hip_runtime.h>

// Profile-HMM forward (log2-domain) + KLD, MI355X.
// v5: COLUMN-banded decomposition. One wave per batch element; lane i owns
// sequence columns c = 4i+1..4i+4. At step s, lane i computes state-row
// k = s-i for its 4 columns (anti-diagonal over the (k,c) grid).
//   fM[k][c] needs row k-1 @ c-1  -> own regs (cc>=1) / 2-step-old bperm (cc=0)
//   fD[k][c] needs row k-1 @ c    -> own regs (no shuffle)
//   fI[k][c] needs row k   @ c-1  -> this-step serial chain / 1-step-old bperm
// => the 3 bpermutes/step have >=1 step of slack: latency pipelined, not serial.
// Row-k params stream from LDS (stride 7/5 => conflict-free), prefetched 1 step.
// Row-0 insert recurrence solved in closed form (identical-link geometric sum).

constexpr float LOG2E = 1.4426950408889634f;
constexpr float LN2   = 0.6931471805599453f;
constexpr float NEG2  = -144.26950408889634f; // -100*LOG2E
constexpr float LQ2   = -2.0f;                // log2(0.25)

// log2(1+e) on [0,1]: Taylor @ e=0.5, deg 5 (max err ~5e-4)
constexpr float K0 = 0.5849625007f, K1 = 0.9617966939f, K2 = -0.3205988980f,
                K3 = 0.1424883991f, K4 = -0.0712441995f, K5 = 0.0379969064f;
// log2(s) on [1,3] via v=s-2: Taylor @ s=2, deg 6 (max err ~3e-3)
constexpr float M0 = 1.0f, M1 = 0.7213475204f, M2 = -0.1803368801f,
                M3 = 0.0601122934f, M4 = -0.0225421100f, M5 = 0.0090168440f,
                M6 = -0.0037570184f;

__device__ __forceinline__ float exp2_hw(float x) {
    float r; asm("v_exp_f32 %0, %1" : "=v"(r) : "v"(x)); return r;
}
__device__ __forceinline__ float plog1p(float e) { // log2(1+e), e in [0,1]
    float u = e - 0.5f, u2 = u * u;
    float a = fmaf(u, K1, K0), b = fmaf(u, K3, K2), c = fmaf(u, K5, K4);
    return fmaf(u2, fmaf(u2, c, b), a);
}
__device__ __forceinline__ float lae2(float x, float y) { // log2(2^x + 2^y)
    float m = fmaxf(x, y);
    float d = x - y;
    float e = exp2_hw(fminf(d, -d));
    return m + plog1p(e);
}
__device__ __forceinline__ float lse3(float p, float q, float r) {
    float m = fmaxf(fmaxf(p, q), r);
    float s = exp2_hw(p - m) + exp2_hw(q - m) + exp2_hw(r - m); // [1,3]
    float v = s - 2.0f, v2 = v * v;
    float A = fmaf(v, M1, M0), B = fmaf(v, M3, M2), C = fmaf(v, M5, M4);
    float CD = fmaf(v2, M6, C);
    return m + fmaf(v2, fmaf(v2, CD, B), A);
}
// log2(sum_{t=0}^{n-1} 2^{t*g}), n>=1. Init-only (libm ok).
__device__ float geom_log2(int n, float g) {
    if (n <= 1) return 0.0f;
    float nf = (float)n;
    if (g > 0.01f)
        return (nf - 1.0f) * g + log2f((1.0f - exp2f(-nf * g)) / (1.0f - exp2f(-g)));
    if (g < -0.01f)
        return log2f((1.0f - exp2f(nf * g)) / (1.0f - exp2f(g)));
    return log2f(expm1f(nf * g * LN2) / expm1f(g * LN2));
}

// transitions: (B, 129, 7)  M2M=0 M2I=1 M2D=2 I2M=3 I2I=4 D2M=5 D2D=6
// emissions:   (B, 128, 4);  tokens: (B, 256) int32 in [0,4)
__global__ __launch_bounds__(64) void phmm_fwd(const int* __restrict__ tokens,
                                               const float* __restrict__ trans,
                                               const float* __restrict__ emis,
                                               float* __restrict__ nll_out)
{
    const int b = blockIdx.x;
    const int i = threadIdx.x;
    const int up4 = (i - 1) * 4; // bperm addr (lane 0 wraps; overridden)

    __shared__ float ldsT[903]; // 129 rows x 7, *LOG2E, LQ2 folded into M2I/I2I
    __shared__ float ldsE[640]; // 128 rows x 5 (pad), *LOG2E
    {
        const float* gT = trans + (size_t)b * 903;
        for (int t = i; t < 903; t += 64) {
            int r = t % 7;
            float v = gT[t] * LOG2E;
            if (r == 1 || r == 4) v += LQ2;
            ldsT[t] = v;
        }
        const float* gE = emis + (size_t)b * 512;
        for (int t = i; t < 512; t += 64)
            ldsE[(t >> 2) * 5 + (t & 3)] = gE[t] * LOG2E;
    }
    const int4 tk = ((const int4*)(tokens + (size_t)b * 256))[i]; // cols 4i+1..4i+4
    __syncthreads();

    // Row-0 insert recurrence, closed form:
    // fI0[1] = lae2(a0mi + 0, a0ii + NEG2); for c>=2: fI0[c] = lae2(alpha, gamma + fI0[c-1])
    const float a0mi = ldsT[1]; // a[0][M2I]*LOG2E + LQ2
    const float a0ii = ldsT[4]; // a[0][I2I]*LOG2E + LQ2
    const float alpha = a0mi + NEG2;
    const float gamma = a0ii;
    const float fI01 = lae2(a0mi, a0ii + NEG2);
    float fi0[4];
    #pragma unroll
    for (int cc = 0; cc < 4; ++cc) {
        const int n = 4 * i + cc; // links applied to fI0[1] for column m=n+1
        fi0[cc] = (n == 0) ? fI01
                           : lae2(alpha + geom_log2(n, gamma), (float)n * gamma + fI01);
    }

    // Row registers: row k-1 values at own columns 4i+1..4i+4 (init = row 0)
    float rM0 = NEG2, rM1 = NEG2, rM2 = NEG2, rM3 = NEG2;
    float rI0 = fi0[0], rI1 = fi0[1], rI2 = fi0[2], rI3 = fi0[3];
    float rD0 = NEG2, rD1 = NEG2, rD2 = NEG2, rD3 = NEG2;
    float eM = NEG2, eI = fi0[3], eD = NEG2;  // edge (own col 4i+4), current row
    float sM = NEG2, sI = NEG2, sD = NEG2;    // saved bperm (neighbor row k-1 @ 4i)
    float fD0 = NEG2;                         // fD[k-1][col0] chain (lane 0)

    // Prefetched params for step s=1 (k = 1-i):
    float p_mm = ldsT[0], p_md = ldsT[2], p_im = ldsT[3], p_dm = ldsT[5], p_dd = ldsT[6]; // row k-1 (=row 0)
    const int kf = (i == 0) ? 7 : 0;          // row clamp(1-i,0,128)*7
    float f_mm = ldsT[kf + 0], f_mi = ldsT[kf + 1], f_md = ldsT[kf + 2],
          f_im = ldsT[kf + 3], f_ii = ldsT[kf + 4], f_dm = ldsT[kf + 5],
          f_dd = ldsT[kf + 6];                // row k (fresh)
    const int so0 = tk.x, so1 = tk.y, so2 = tk.z, so3 = tk.w;
    float e0 = ldsE[so0], e1 = ldsE[so1], e2 = ldsE[so2], e3 = ldsE[so3]; // e row 0

    int k = 1 - i;
    #pragma unroll 1
    for (int s = 1; s <= 191; ++s) {
        // sample neighbor edges (their row (s-1)-(i-1) = own k); slack >= 1 step
        const float qM = __int_as_float(__builtin_amdgcn_ds_bpermute(up4, __float_as_int(eM)));
        const float qI = __int_as_float(__builtin_amdgcn_ds_bpermute(up4, __float_as_int(eI)));
        const float qD = __int_as_float(__builtin_amdgcn_ds_bpermute(up4, __float_as_int(eD)));
        // lane-0 boundary (column 0 = initial state)
        const float mprev0 = (k == 1) ? 0.0f : NEG2; // fM[k-1][0]
        float usM = sM, usI = sI, usD = sD, uqM = qM, uqI = qI;
        if (i == 0) { usM = mprev0; usI = NEG2; usD = fD0; uqM = NEG2; uqI = NEG2; }
        // M cells (row k-1 @ c-1; emission e[k-1][sym_c])
        const float nM0 = e0 + lse3(p_mm + usM, p_im + usI, p_dm + usD);
        const float nM1 = e1 + lse3(p_mm + rM0, p_im + rI0, p_dm + rD0);
        const float nM2 = e2 + lse3(p_mm + rM1, p_im + rI1, p_dm + rD1);
        const float nM3 = e3 + lse3(p_mm + rM2, p_im + rI2, p_dm + rD2);
        // D cells (row k-1 @ same column)
        const float nD0 = lae2(p_md + rM0, p_dd + rD0);
        const float nD1 = lae2(p_md + rM1, p_dd + rD1);
        const float nD2 = lae2(p_md + rM2, p_dd + rD2);
        const float nD3 = lae2(p_md + rM3, p_dd + rD3);
        // I cells (row k @ c-1; serial in-band; LQ2 pre-folded into f_mi/f_ii)
        const float nI0 = lae2(f_mi + uqM, f_ii + uqI);
        const float nI1 = lae2(f_mi + nM0, f_ii + nI0);
        const float nI2 = lae2(f_mi + nM1, f_ii + nI1);
        const float nI3 = lae2(f_mi + nM2, f_ii + nI2);
        // lane-0 col-0 delete chain: fD[k][0] from fD[k-1][0]
        fD0 = lae2(p_md + mprev0, p_dd + fD0);
        // masked writeback (active iff 1 <= k <= 128)
        const bool act = ((unsigned)(k - 1)) < 128u;
        rM0 = act ? nM0 : rM0; rM1 = act ? nM1 : rM1;
        rM2 = act ? nM2 : rM2; rM3 = act ? nM3 : rM3;
        rI0 = act ? nI0 : rI0; rI1 = act ? nI1 : rI1;
        rI2 = act ? nI2 : rI2; rI3 = act ? nI3 : rI3;
        rD0 = act ? nD0 : rD0; rD1 = act ? nD1 : rD1;
        rD2 = act ? nD2 : rD2; rD3 = act ? nD3 : rD3;
        eM = rM3; eI = rI3; eD = rD3;
        sM = qM; sI = qI; sD = qD;
        // rotate fresh -> prev; prefetch step s+1 params (row k+1, e row k)
        p_mm = f_mm; p_md = f_md; p_im = f_im; p_dm = f_dm; p_dd = f_dd;
        ++k;
        int kc = k < 0 ? 0 : (k > 128 ? 128 : k);
        int ke = k - 1 < 0 ? 0 : (k - 1 > 127 ? 127 : k - 1);
        const float* Tr = &ldsT[kc * 7];
        f_mm = Tr[0]; f_mi = Tr[1]; f_md = Tr[2]; f_im = Tr[3];
        f_ii = Tr[4]; f_dm = Tr[5]; f_dd = Tr[6];
        const float* Er = &ldsE[ke * 5];
        e0 = Er[so0]; e1 = Er[so1]; e2 = Er[so2]; e3 = Er[so3];
    }

    // lane 63 holds row 128 @ col 256 in (rM3,rI3,rD3); p_* = row 128 after loop
    const float fin = lse3(rM3 + p_mm, rI3 + p_im, rD3 + p_dm);
    if (i == 63) nll_out[b] = -fin * LN2;
}

__global__ __launch_bounds__(256) void phmm_finish(const float* __restrict__ nll,
                                                   const float* __restrict__ mus,
                                                   const float* __restrict__ logvars,
                                                   float* __restrict__ out)
{
    const int tid = threadIdx.x;
    float acc = 0.0f;
    for (int idx = tid; idx < 512; idx += 256) acc += nll[idx];
    for (int idx = tid; idx < 8192; idx += 256) {
        const float mu = mus[idx], lv = logvars[idx];
        acc -= 0.5f * (1.0f + lv - mu * mu - exp2_hw(lv * LOG2E));
    }
    #pragma unroll
    for (int off = 32; off >= 1; off >>= 1) acc += __shfl_down(acc, off);
    __shared__ float red[4];
    if ((tid & 63) == 0) red[tid >> 6] = acc;
    __syncthreads();
    if (tid == 0) out[0] = (red[0] + red[1] + red[2] + red[3]) * (1.0f / 512.0f);
}

extern "C" void kernel_launch(void* const* d_in, const int* in_sizes, int n_in,
                              void* d_out, int out_size, void* d_ws, size_t ws_size,
                              hipStream_t stream)
{
    const int*   tokens  = (const int*)d_in[0];   // (512, 256) int32
    const float* trans   = (const float*)d_in[1]; // (512, 129, 7) f32
    const float* emis    = (const float*)d_in[2]; // (512, 128, 4) f32
    const float* mus     = (const float*)d_in[3]; // (512, 16) f32
    const float* logvars = (const float*)d_in[4]; // (512, 16) f32
    float* nll = (float*)d_ws;                    // 512 floats scratch

    phmm_fwd<<<dim3(512), dim3(64), 0, stream>>>(tokens, trans, emis, nll);
    phmm_finish<<<dim3(1), dim3(256), 0, stream>>>(nll, mus, logvars, (float*)d_out);
}

// Round 6
// 109.079 us; speedup vs baseline: 1.3114x; 1.0361x over previous
//
#include <hip/hip_runtime.h>

// Profile-HMM forward (log2-domain) + KLD, MI355X.
// v6 = v5 with ONE change: exp2 via __builtin_amdgcn_exp2f (latency-modeled)
// instead of inline asm (which LLVM schedules as 1-cycle, exposing ~50 cyc
// of trans latency per logaddexp at 1 wave/SIMD).
//
// v5 structure: COLUMN-banded decomposition. One wave per batch element;
// lane i owns sequence columns c = 4i+1..4i+4. At step s, lane i computes
// state-row k = s-i for its 4 columns (anti-diagonal over the (k,c) grid).

constexpr float LOG2E = 1.4426950408889634f;
constexpr float LN2   = 0.6931471805599453f;
constexpr float NEG2  = -144.26950408889634f; // -100*LOG2E
constexpr float LQ2   = -2.0f;                // log2(0.25)

// log2(1+e) on [0,1]: Taylor @ e=0.5, deg 5 (max err ~5e-4)
constexpr float K0 = 0.5849625007f, K1 = 0.9617966939f, K2 = -0.3205988980f,
                K3 = 0.1424883991f, K4 = -0.0712441995f, K5 = 0.0379969064f;
// log2(s) on [1,3] via v=s-2: Taylor @ s=2, deg 6 (max err ~3e-3)
constexpr float M0 = 1.0f, M1 = 0.7213475204f, M2 = -0.1803368801f,
                M3 = 0.0601122934f, M4 = -0.0225421100f, M5 = 0.0090168440f,
                M6 = -0.0037570184f;

__device__ __forceinline__ float exp2_hw(float x) {
#if __has_builtin(__builtin_amdgcn_exp2f)
    return __builtin_amdgcn_exp2f(x);   // v_exp_f32, latency-modeled
#else
    return __exp2f(x);
#endif
}
__device__ __forceinline__ float plog1p(float e) { // log2(1+e), e in [0,1]
    float u = e - 0.5f, u2 = u * u;
    float a = fmaf(u, K1, K0), b = fmaf(u, K3, K2), c = fmaf(u, K5, K4);
    return fmaf(u2, fmaf(u2, c, b), a);
}
__device__ __forceinline__ float lae2(float x, float y) { // log2(2^x + 2^y)
    float m = fmaxf(x, y);
    float d = x - y;
    float e = exp2_hw(fminf(d, -d));
    return m + plog1p(e);
}
__device__ __forceinline__ float lse3(float p, float q, float r) {
    float m = fmaxf(fmaxf(p, q), r);
    float s = exp2_hw(p - m) + exp2_hw(q - m) + exp2_hw(r - m); // [1,3]
    float v = s - 2.0f, v2 = v * v;
    float A = fmaf(v, M1, M0), B = fmaf(v, M3, M2), C = fmaf(v, M5, M4);
    float CD = fmaf(v2, M6, C);
    return m + fmaf(v2, fmaf(v2, CD, B), A);
}
// log2(sum_{t=0}^{n-1} 2^{t*g}), n>=1. Init-only (libm ok).
__device__ float geom_log2(int n, float g) {
    if (n <= 1) return 0.0f;
    float nf = (float)n;
    if (g > 0.01f)
        return (nf - 1.0f) * g + log2f((1.0f - exp2f(-nf * g)) / (1.0f - exp2f(-g)));
    if (g < -0.01f)
        return log2f((1.0f - exp2f(nf * g)) / (1.0f - exp2f(g)));
    return log2f(expm1f(nf * g * LN2) / expm1f(g * LN2));
}

// transitions: (B, 129, 7)  M2M=0 M2I=1 M2D=2 I2M=3 I2I=4 D2M=5 D2D=6
// emissions:   (B, 128, 4);  tokens: (B, 256) int32 in [0,4)
__global__ __launch_bounds__(64) void phmm_fwd(const int* __restrict__ tokens,
                                               const float* __restrict__ trans,
                                               const float* __restrict__ emis,
                                               float* __restrict__ nll_out)
{
    const int b = blockIdx.x;
    const int i = threadIdx.x;
    const int up4 = (i - 1) * 4; // bperm addr (lane 0 wraps; overridden)

    __shared__ float ldsT[903]; // 129 rows x 7, *LOG2E, LQ2 folded into M2I/I2I
    __shared__ float ldsE[640]; // 128 rows x 5 (pad), *LOG2E
    {
        const float* gT = trans + (size_t)b * 903;
        for (int t = i; t < 903; t += 64) {
            int r = t % 7;
            float v = gT[t] * LOG2E;
            if (r == 1 || r == 4) v += LQ2;
            ldsT[t] = v;
        }
        const float* gE = emis + (size_t)b * 512;
        for (int t = i; t < 512; t += 64)
            ldsE[(t >> 2) * 5 + (t & 3)] = gE[t] * LOG2E;
    }
    const int4 tk = ((const int4*)(tokens + (size_t)b * 256))[i]; // cols 4i+1..4i+4
    __syncthreads();

    // Row-0 insert recurrence, closed form:
    // fI0[1] = lae2(a0mi + 0, a0ii + NEG2); for c>=2: fI0[c] = lae2(alpha, gamma + fI0[c-1])
    const float a0mi = ldsT[1]; // a[0][M2I]*LOG2E + LQ2
    const float a0ii = ldsT[4]; // a[0][I2I]*LOG2E + LQ2
    const float alpha = a0mi + NEG2;
    const float gamma = a0ii;
    const float fI01 = lae2(a0mi, a0ii + NEG2);
    float fi0[4];
    #pragma unroll
    for (int cc = 0; cc < 4; ++cc) {
        const int n = 4 * i + cc; // links applied to fI0[1] for column m=n+1
        fi0[cc] = (n == 0) ? fI01
                           : lae2(alpha + geom_log2(n, gamma), (float)n * gamma + fI01);
    }

    // Row registers: row k-1 values at own columns 4i+1..4i+4 (init = row 0)
    float rM0 = NEG2, rM1 = NEG2, rM2 = NEG2, rM3 = NEG2;
    float rI0 = fi0[0], rI1 = fi0[1], rI2 = fi0[2], rI3 = fi0[3];
    float rD0 = NEG2, rD1 = NEG2, rD2 = NEG2, rD3 = NEG2;
    float eM = NEG2, eI = fi0[3], eD = NEG2;  // edge (own col 4i+4), current row
    float sM = NEG2, sI = NEG2, sD = NEG2;    // saved bperm (neighbor row k-1 @ 4i)
    float fD0 = NEG2;                         // fD[k-1][col0] chain (lane 0)

    // Prefetched params for step s=1 (k = 1-i):
    float p_mm = ldsT[0], p_md = ldsT[2], p_im = ldsT[3], p_dm = ldsT[5], p_dd = ldsT[6]; // row k-1 (=row 0)
    const int kf = (i == 0) ? 7 : 0;          // row clamp(1-i,0,128)*7
    float f_mm = ldsT[kf + 0], f_mi = ldsT[kf + 1], f_md = ldsT[kf + 2],
          f_im = ldsT[kf + 3], f_ii = ldsT[kf + 4], f_dm = ldsT[kf + 5],
          f_dd = ldsT[kf + 6];                // row k (fresh)
    const int so0 = tk.x, so1 = tk.y, so2 = tk.z, so3 = tk.w;
    float e0 = ldsE[so0], e1 = ldsE[so1], e2 = ldsE[so2], e3 = ldsE[so3]; // e row 0

    int k = 1 - i;
    #pragma unroll 1
    for (int s = 1; s <= 191; ++s) {
        // sample neighbor edges (their row (s-1)-(i-1) = own k); slack >= 1 step
        const float qM = __int_as_float(__builtin_amdgcn_ds_bpermute(up4, __float_as_int(eM)));
        const float qI = __int_as_float(__builtin_amdgcn_ds_bpermute(up4, __float_as_int(eI)));
        const float qD = __int_as_float(__builtin_amdgcn_ds_bpermute(up4, __float_as_int(eD)));
        // lane-0 boundary (column 0 = initial state)
        const float mprev0 = (k == 1) ? 0.0f : NEG2; // fM[k-1][0]
        float usM = sM, usI = sI, usD = sD, uqM = qM, uqI = qI;
        if (i == 0) { usM = mprev0; usI = NEG2; usD = fD0; uqM = NEG2; uqI = NEG2; }
        // M cells (row k-1 @ c-1; emission e[k-1][sym_c])
        const float nM0 = e0 + lse3(p_mm + usM, p_im + usI, p_dm + usD);
        const float nM1 = e1 + lse3(p_mm + rM0, p_im + rI0, p_dm + rD0);
        const float nM2 = e2 + lse3(p_mm + rM1, p_im + rI1, p_dm + rD1);
        const float nM3 = e3 + lse3(p_mm + rM2, p_im + rI2, p_dm + rD2);
        // D cells (row k-1 @ same column)
        const float nD0 = lae2(p_md + rM0, p_dd + rD0);
        const float nD1 = lae2(p_md + rM1, p_dd + rD1);
        const float nD2 = lae2(p_md + rM2, p_dd + rD2);
        const float nD3 = lae2(p_md + rM3, p_dd + rD3);
        // I cells (row k @ c-1; serial in-band; LQ2 pre-folded into f_mi/f_ii)
        const float nI0 = lae2(f_mi + uqM, f_ii + uqI);
        const float nI1 = lae2(f_mi + nM0, f_ii + nI0);
        const float nI2 = lae2(f_mi + nM1, f_ii + nI1);
        const float nI3 = lae2(f_mi + nM2, f_ii + nI2);
        // lane-0 col-0 delete chain: fD[k][0] from fD[k-1][0]
        fD0 = lae2(p_md + mprev0, p_dd + fD0);
        // masked writeback (active iff 1 <= k <= 128)
        const bool act = ((unsigned)(k - 1)) < 128u;
        rM0 = act ? nM0 : rM0; rM1 = act ? nM1 : rM1;
        rM2 = act ? nM2 : rM2; rM3 = act ? nM3 : rM3;
        rI0 = act ? nI0 : rI0; rI1 = act ? nI1 : rI1;
        rI2 = act ? nI2 : rI2; rI3 = act ? nI3 : rI3;
        rD0 = act ? nD0 : rD0; rD1 = act ? nD1 : rD1;
        rD2 = act ? nD2 : rD2; rD3 = act ? nD3 : rD3;
        eM = rM3; eI = rI3; eD = rD3;
        sM = qM; sI = qI; sD = qD;
        // rotate fresh -> prev; prefetch step s+1 params (row k+1, e row k)
        p_mm = f_mm; p_md = f_md; p_im = f_im; p_dm = f_dm; p_dd = f_dd;
        ++k;
        int kc = k < 0 ? 0 : (k > 128 ? 128 : k);
        int ke = k - 1 < 0 ? 0 : (k - 1 > 127 ? 127 : k - 1);
        const float* Tr = &ldsT[kc * 7];
        f_mm = Tr[0]; f_mi = Tr[1]; f_md = Tr[2]; f_im = Tr[3];
        f_ii = Tr[4]; f_dm = Tr[5]; f_dd = Tr[6];
        const float* Er = &ldsE[ke * 5];
        e0 = Er[so0]; e1 = Er[so1]; e2 = Er[so2]; e3 = Er[so3];
    }

    // lane 63 holds row 128 @ col 256 in (rM3,rI3,rD3); p_* = row 128 after loop
    const float fin = lse3(rM3 + p_mm, rI3 + p_im, rD3 + p_dm);
    if (i == 63) nll_out[b] = -fin * LN2;
}

__global__ __launch_bounds__(256) void phmm_finish(const float* __restrict__ nll,
                                                   const float* __restrict__ mus,
                                                   const float* __restrict__ logvars,
                                                   float* __restrict__ out)
{
    const int tid = threadIdx.x;
    float acc = 0.0f;
    for (int idx = tid; idx < 512; idx += 256) acc += nll[idx];
    for (int idx = tid; idx < 8192; idx += 256) {
        const float mu = mus[idx], lv = logvars[idx];
        acc -= 0.5f * (1.0f + lv - mu * mu - exp2_hw(lv * LOG2E));
    }
    #pragma unroll
    for (int off = 32; off >= 1; off >>= 1) acc += __shfl_down(acc, off);
    __shared__ float red[4];
    if ((tid & 63) == 0) red[tid >> 6] = acc;
    __syncthreads();
    if (tid == 0) out[0] = (red[0] + red[1] + red[2] + red[3]) * (1.0f / 512.0f);
}

extern "C" void kernel_launch(void* const* d_in, const int* in_sizes, int n_in,
                              void* d_out, int out_size, void* d_ws, size_t ws_size,
                              hipStream_t stream)
{
    const int*   tokens  = (const int*)d_in[0];   // (512, 256) int32
    const float* trans   = (const float*)d_in[1]; // (512, 129, 7) f32
    const float* emis    = (const float*)d_in[2]; // (512, 128, 4) f32
    const float* mus     = (const float*)d_in[3]; // (512, 16) f32
    const float* logvars = (const float*)d_in[4]; // (512, 16) f32
    float* nll = (float*)d_ws;                    // 512 floats scratch

    phmm_fwd<<<dim3(512), dim3(64), 0, stream>>>(tokens, trans, emis, nll);
    phmm_finish<<<dim3(1), dim3(256), 0, stream>>>(nll, mus, logvars, (float*)d_out);
}

// Round 7
// 77.691 us; speedup vs baseline: 1.8412x; 1.4040x over previous
//
#include <hip/hip_runtime.h>

// Profile-HMM forward (log2-domain) + KLD, MI355X.
// v7 = v3 structure with ONE change: all cross-lane shuffles via DPP
// wave_shr:1 (VALU pipe, ~2-4 cyc, no lgkmcnt) instead of ds_bpermute
// (LDS queue, ~70-130 cyc effectively serialized at 1 wave/SIMD).
//
// Structure: one wave per batch element; lane i owns states k1=2i+1, k2=2i+2.
// Skewed schedule: at step s, lane i computes COLUMN c = s - i.

constexpr float LOG2E = 1.4426950408889634f;
constexpr float LN2   = 0.6931471805599453f;
constexpr float NEG2  = -144.26950408889634f; // -100*LOG2E
constexpr float LQ2   = -2.0f;                // log2(0.25)

// log2(1+e) on [0,1]: Taylor @ e=0.5, deg 5 (max err ~5e-4)
constexpr float K0 = 0.5849625007f, K1 = 0.9617966939f, K2 = -0.3205988980f,
                K3 = 0.1424883991f, K4 = -0.0712441995f, K5 = 0.0379969064f;
// log2(s) on [1,3] via v=s-2: Taylor @ s=2, deg 6 (max err ~3e-3)
constexpr float M0 = 1.0f, M1 = 0.7213475204f, M2 = -0.1803368801f,
                M3 = 0.0601122934f, M4 = -0.0225421100f, M5 = 0.0090168440f,
                M6 = -0.0037570184f;

typedef float v2f __attribute__((ext_vector_type(2)));

__device__ __forceinline__ float exp2_hw(float x) {
#if __has_builtin(__builtin_amdgcn_exp2f)
    return __builtin_amdgcn_exp2f(x);
#else
    return __exp2f(x);
#endif
}
__device__ __forceinline__ float plog1p(float e) { // log2(1+e), e in [0,1]
    float u = e - 0.5f, u2 = u * u;
    float a = fmaf(u, K1, K0), b = fmaf(u, K3, K2), c = fmaf(u, K5, K4);
    return fmaf(u2, fmaf(u2, c, b), a);
}
__device__ __forceinline__ float lae2(float x, float y) { // log2(2^x + 2^y)
    float m = fmaxf(x, y);
    float d = x - y;
    float e = exp2_hw(fminf(d, -d));
    return m + plog1p(e);
}
__device__ __forceinline__ float lse3(float p, float q, float r) {
    float m = fmaxf(fmaxf(p, q), r);
    float s = exp2_hw(p - m) + exp2_hw(q - m) + exp2_hw(r - m); // [1,3]
    float v = s - 2.0f, v2 = v * v;
    float A = fmaf(v, M1, M0), B = fmaf(v, M3, M2), C = fmaf(v, M5, M4);
    float CD = fmaf(v2, M6, C);
    return m + fmaf(v2, fmaf(v2, CD, B), A);
}
__device__ __forceinline__ v2f lae2_pk(v2f x, v2f y) {
    v2f m; m.x = fmaxf(x.x, y.x); m.y = fmaxf(x.y, y.y);
    v2f d = x - y;
    v2f e; e.x = exp2_hw(fminf(d.x, -d.x)); e.y = exp2_hw(fminf(d.y, -d.y));
    v2f u  = e - 0.5f;
    v2f u2 = u * u;
    v2f a = u * K1 + K0;
    v2f b = u * K3 + K2;
    v2f c = u * K5 + K4;
    return m + (u2 * (u2 * c + b) + a);
}
__device__ __forceinline__ v2f lse3_pk(v2f p, v2f q, v2f r) {
    v2f m; m.x = fmaxf(fmaxf(p.x, q.x), r.x); m.y = fmaxf(fmaxf(p.y, q.y), r.y);
    v2f sp = p - m, sq = q - m, sr = r - m;
    v2f s;
    s.x = exp2_hw(sp.x) + exp2_hw(sq.x) + exp2_hw(sr.x);
    s.y = exp2_hw(sp.y) + exp2_hw(sq.y) + exp2_hw(sr.y);
    v2f v  = s - 2.0f;
    v2f v2_ = v * v;
    v2f A  = v * M1 + M0;
    v2f B  = v * M3 + M2;
    v2f C  = v * M5 + M4;
    v2f CD = v2_ * M6 + C;
    return m + (v2_ * (v2_ * CD + B) + A);
}

// DPP wave_shr:1 — lane i gets lane i-1's src; lane 0 gets `old_`.
__device__ __forceinline__ int dppi_shr1(int old_, int src) {
    return __builtin_amdgcn_update_dpp(old_, src, 0x138, 0xF, 0xF, false);
}
__device__ __forceinline__ float dppf_shr1(float old_, float src) {
    return __int_as_float(dppi_shr1(__float_as_int(old_), __float_as_int(src)));
}

// Per-step update. q* = neighbor state @ col c (this step's shift);
// p* = neighbor state @ col c-1 (saved from last step's shift).
// Lane-0 boundaries baked into DPP `old`: qM/qD -> NEG2 (fM[0]/fD[0] for c>=1),
// tok -> FRESH. Only nbI needs a runtime lane-0 override (fI0 recurrence).
#define STEP(S, FRESH, MODE) do {                                              \
    const float qM = dppf_shr1(NEG2, cM2);                                     \
    const float qI = dppf_shr1(NEG2, cI2);                                     \
    const float qD = dppf_shr1(NEG2, cD2);                                     \
    const int   tq = dppi_shr1((FRESH), tok);                                  \
    const bool isS1 = ((MODE) == 0) && ((S) == 1);                             \
    const float nbM = pM;                                                      \
    const float nbI = lane0 ? fI0 : pI;                                        \
    const float nbD = pD;                                                      \
    tok = tq;                                                                  \
    const int sym = tok;                                                       \
    const float e1 = (sym & 2) ? ((sym & 1) ? em1.w : em1.z)                   \
                               : ((sym & 1) ? em1.y : em1.x);                  \
    const float e2 = (sym & 2) ? ((sym & 1) ? em2.w : em2.z)                   \
                               : ((sym & 1) ? em2.y : em2.x);                  \
    v2f P_, Q_, R_;                                                            \
    P_.x = aM2M0 + nbM; P_.y = aM2M1 + cM1;                                    \
    Q_.x = aI2M0 + nbI; Q_.y = aI2M1 + cI1;                                    \
    R_.x = aD2M0 + nbD; R_.y = aD2M1 + cD1;                                    \
    const v2f nMv = lse3_pk(P_, Q_, R_);                                       \
    const float nM1 = nMv.x + e1;                                              \
    const float nM2 = nMv.y + e2;                                              \
    v2f X_, Y_;                                                                \
    X_.x = aM2I1 + cM1; X_.y = aM2I2 + cM2;                                    \
    Y_.x = aI2I1 + cI1; Y_.y = aI2I2 + cI2;                                    \
    const v2f nIv = lae2_pk(X_, Y_);                                           \
    const float nD1 = lae2(aM2D0 + qM, aD2D0 + qD);                            \
    const float nD2 = lae2(aM2D1 + nM1, aD2D1 + nD1);                          \
    const float nI0v = lae2(isS1 ? A0 : A0p, B0 + fI0);                        \
    if ((MODE) == 1) {                                                         \
        cM1 = nM1; cM2 = nM2; cI1 = nIv.x; cI2 = nIv.y; cD1 = nD1; cD2 = nD2;  \
    } else if ((MODE) == 0) {                                                  \
        const int c = (S) - i;                                                 \
        const bool act = (c >= 1), actD = (c >= 0);                            \
        cM1 = act  ? nM1   : cM1; cM2 = act  ? nM2   : cM2;                    \
        cI1 = act  ? nIv.x : cI1; cI2 = act  ? nIv.y : cI2;                    \
        cD1 = actD ? nD1   : cD1; cD2 = actD ? nD2   : cD2;                    \
    } else {                                                                   \
        const int c = (S) - i;                                                 \
        const bool act = (c <= 256);                                           \
        cM1 = act ? nM1   : cM1; cM2 = act ? nM2   : cM2;                      \
        cI1 = act ? nIv.x : cI1; cI2 = act ? nIv.y : cI2;                      \
        cD1 = act ? nD1   : cD1; cD2 = act ? nD2   : cD2;                      \
    }                                                                          \
    pM = qM; pI = qI; pD = qD;                                                 \
    fI0 = nI0v;                                                                \
} while (0)

// transitions: (B, 129, 7)  M2M=0 M2I=1 M2D=2 I2M=3 I2I=4 D2M=5 D2D=6
// emissions:   (B, 128, 4);  tokens: (B, 256) int32 in [0,4)
__global__ __launch_bounds__(64) void phmm_fwd(const int* __restrict__ tokens,
                                               const float* __restrict__ trans,
                                               const float* __restrict__ emis,
                                               float* __restrict__ nll_out)
{
    const int b = blockIdx.x;
    const int i = threadIdx.x;
    const bool lane0 = (i == 0);

    const float* ab = trans + (size_t)b * 903;
    const int r0 = (2 * i) * 7, r1 = (2 * i + 1) * 7, r2 = (2 * i + 2) * 7;

    const float aM2M0 = ab[r0 + 0] * LOG2E, aI2M0 = ab[r0 + 3] * LOG2E, aD2M0 = ab[r0 + 5] * LOG2E;
    const float aM2D0 = ab[r0 + 2] * LOG2E, aD2D0 = ab[r0 + 6] * LOG2E;
    const float aM2M1 = ab[r1 + 0] * LOG2E, aI2M1 = ab[r1 + 3] * LOG2E, aD2M1 = ab[r1 + 5] * LOG2E;
    const float aM2D1 = ab[r1 + 2] * LOG2E, aD2D1 = ab[r1 + 6] * LOG2E;
    const float aM2I1 = ab[r1 + 1] * LOG2E + LQ2, aI2I1 = ab[r1 + 4] * LOG2E + LQ2;
    const float aM2I2 = ab[r2 + 1] * LOG2E + LQ2, aI2I2 = ab[r2 + 4] * LOG2E + LQ2;
    const float A0 = ab[1] * LOG2E + LQ2, B0 = ab[4] * LOG2E + LQ2;
    const float A0p = A0 + NEG2; // fM0 = NEG for columns >= 1
    const float aKM2M = ab[128 * 7 + 0] * LOG2E, aKI2M = ab[128 * 7 + 3] * LOG2E,
                aKD2M = ab[128 * 7 + 5] * LOG2E;

    const float4* eb = (const float4*)(emis + (size_t)b * 512);
    float4 em1 = eb[2 * i];
    float4 em2 = eb[2 * i + 1];
    em1.x *= LOG2E; em1.y *= LOG2E; em1.z *= LOG2E; em1.w *= LOG2E;
    em2.x *= LOG2E; em2.y *= LOG2E; em2.z *= LOG2E; em2.w *= LOG2E;

    const int4 tok_store = ((const int4*)(tokens + (size_t)b * 256))[i];

    // State (log2 units)
    float cM1 = NEG2, cM2 = NEG2, cI1 = NEG2, cI2 = NEG2;
    float pM = lane0 ? 0.0f : NEG2; // fM[0][0] = 0 seeds step 1
    float pI = NEG2, pD = NEG2;
    float fI0 = NEG2;               // fI[0][c-1] (all lanes track, wave-uniform)
    // lane 0's column-0 delete chain (fM[0]@col0 = 0)
    const float d1_0 = lae2(aM2D0 + 0.0f, aD2D0 + NEG2);
    const float d2_0 = lae2(aM2D1 + NEG2, aD2D1 + d1_0);
    float cD1 = lane0 ? d1_0 : NEG2;
    float cD2 = lane0 ? d2_0 : NEG2;
    int tok = 0;

    // steps s = 1 .. 320; lane i active for s in [i+1, i+256]; D-init at s == i.
    #pragma unroll 1
    for (int u = 0; u < 16; ++u) {          // s in [1,64]: fill
        const int f0 = __builtin_amdgcn_readlane(tok_store.x, u);
        const int f1 = __builtin_amdgcn_readlane(tok_store.y, u);
        const int f2 = __builtin_amdgcn_readlane(tok_store.z, u);
        const int f3 = __builtin_amdgcn_readlane(tok_store.w, u);
        const int s0 = 1 + 4 * u;
        STEP(s0 + 0, f0, 0); STEP(s0 + 1, f1, 0);
        STEP(s0 + 2, f2, 0); STEP(s0 + 3, f3, 0);
    }
    #pragma unroll 1
    for (int u = 16; u < 64; ++u) {         // s in [65,256]: steady, all active
        const int f0 = __builtin_amdgcn_readlane(tok_store.x, u);
        const int f1 = __builtin_amdgcn_readlane(tok_store.y, u);
        const int f2 = __builtin_amdgcn_readlane(tok_store.z, u);
        const int f3 = __builtin_amdgcn_readlane(tok_store.w, u);
        const int s0 = 1 + 4 * u;
        STEP(s0 + 0, f0, 1); STEP(s0 + 1, f1, 1);
        STEP(s0 + 2, f2, 1); STEP(s0 + 3, f3, 1);
    }
    #pragma unroll 1
    for (int u = 64; u < 80; ++u) {         // s in [257,320]: drain
        const int s0 = 1 + 4 * u;
        STEP(s0 + 0, 0, 2); STEP(s0 + 1, 0, 2);
        STEP(s0 + 2, 0, 2); STEP(s0 + 3, 0, 2);
    }

    const float fin = lse3(cM2 + aKM2M, cI2 + aKI2M, cD2 + aKD2M);
    if (i == 63) nll_out[b] = -fin * LN2;
}

__global__ __launch_bounds__(256) void phmm_finish(const float* __restrict__ nll,
                                                   const float* __restrict__ mus,
                                                   const float* __restrict__ logvars,
                                                   float* __restrict__ out)
{
    const int tid = threadIdx.x;
    float acc = 0.0f;
    for (int idx = tid; idx < 512; idx += 256) acc += nll[idx];
    for (int idx = tid; idx < 8192; idx += 256) {
        const float mu = mus[idx], lv = logvars[idx];
        acc -= 0.5f * (1.0f + lv - mu * mu - exp2_hw(lv * LOG2E));
    }
    #pragma unroll
    for (int off = 32; off >= 1; off >>= 1) acc += __shfl_down(acc, off);
    __shared__ float red[4];
    if ((tid & 63) == 0) red[tid >> 6] = acc;
    __syncthreads();
    if (tid == 0) out[0] = (red[0] + red[1] + red[2] + red[3]) * (1.0f / 512.0f);
}

extern "C" void kernel_launch(void* const* d_in, const int* in_sizes, int n_in,
                              void* d_out, int out_size, void* d_ws, size_t ws_size,
                              hipStream_t stream)
{
    const int*   tokens  = (const int*)d_in[0];   // (512, 256) int32
    const float* trans   = (const float*)d_in[1]; // (512, 129, 7) f32
    const float* emis    = (const float*)d_in[2]; // (512, 128, 4) f32
    const float* mus     = (const float*)d_in[3]; // (512, 16) f32
    const float* logvars = (const float*)d_in[4]; // (512, 16) f32
    float* nll = (float*)d_ws;                    // 512 floats scratch

    phmm_fwd<<<dim3(512), dim3(64), 0, stream>>>(tokens, trans, emis, nll);
    phmm_finish<<<dim3(1), dim3(256), 0, stream>>>(nll, mus, logvars, (float*)d_out);
}

// Round 8
// 40.935 us; speedup vs baseline: 3.4945x; 1.8979x over previous
//
#include <hip/hip_runtime.h>

// Profile-HMM forward + KLD, MI355X.
// v8: LINEAR-probability-space recurrence (the DP is linear in prob space;
// log-space is only for range). All exps hoisted to init; the 320-step loop
// contains ZERO transcendentals (prior versions were bound by v_exp_f32 at
// ~60-70 cyc each, effectively non-pipelined at 1 wave/SIMD).
// Range: per-lane exponent counter E; every 4 steps states are renormalized
// by 2^-frexp_exp(anchor) (v_ldexp_f32 / v_frexp_exp, full-rate VALU).
// Cross-lane values convert scales exactly: ldexp(q, E_neighbor - E_own).
// Structure otherwise = v7: one wave/batch, lane i owns states k1=2i+1,
// k2=2i+2, skewed schedule (at step s lane i computes column c = s-i),
// cross-lane via DPP wave_shr:1.

constexpr float LOG2E = 1.4426950408889634f;
constexpr float LN2   = 0.6931471805599453f;

__device__ __forceinline__ float exp2_hw(float x) {
#if __has_builtin(__builtin_amdgcn_exp2f)
    return __builtin_amdgcn_exp2f(x);
#else
    return __exp2f(x);
#endif
}
__device__ __forceinline__ float log2_hw(float x) {
#if __has_builtin(__builtin_amdgcn_logf)
    return __builtin_amdgcn_logf(x);
#else
    return __log2f(x);
#endif
}
__device__ __forceinline__ float ldx(float x, int e) {
#if __has_builtin(__builtin_amdgcn_ldexpf)
    return __builtin_amdgcn_ldexpf(x, e);
#else
    return ldexpf(x, e);
#endif
}
__device__ __forceinline__ int fxe(float x) { // exponent: x = m*2^e, m in [0.5,1); 0 -> 0
#if __has_builtin(__builtin_amdgcn_frexp_expf)
    return __builtin_amdgcn_frexp_expf(x);
#else
    int e; (void)frexpf(x, &e); return e;
#endif
}
// DPP wave_shr:1 — lane i gets lane i-1's src; lane 0 gets `old_`.
__device__ __forceinline__ int dppi_shr1(int old_, int src) {
    return __builtin_amdgcn_update_dpp(old_, src, 0x138, 0xF, 0xF, false);
}
__device__ __forceinline__ float dppf_shr1(float old_, float src) {
    return __int_as_float(dppi_shr1(__float_as_int(old_), __float_as_int(src)));
}

// Per-step update (linear space, own scale 2^E).
// q* = neighbor state @ col c (this step's DPP, rescaled to own E);
// p* = neighbor state @ col c-1 (saved last step, already own-scale).
#define STEP(S, FRESH, MODE) do {                                              \
    const float qMr = dppf_shr1(0.0f, cM2);                                    \
    const float qIr = dppf_shr1(0.0f, cI2);                                    \
    const float qDr = dppf_shr1(0.0f, cD2);                                    \
    const int   qEi = dppi_shr1(0, E);                                         \
    const int   tq  = dppi_shr1((FRESH), tok);                                 \
    const int   dE  = qEi - E;                                                 \
    const float qM = ldx(qMr, dE), qI = ldx(qIr, dE), qD = ldx(qDr, dE);       \
    const bool isS1 = ((MODE) == 0) && ((S) == 1);                             \
    const float nbM = pM;                                                      \
    const float nbI = lane0 ? ldx(fI0, EI0 - E) : pI;                          \
    const float nbD = pD;                                                      \
    tok = tq;                                                                  \
    const int sym = tok;                                                       \
    const float e1 = (sym & 2) ? ((sym & 1) ? el1.w : el1.z)                   \
                               : ((sym & 1) ? el1.y : el1.x);                  \
    const float e2 = (sym & 2) ? ((sym & 1) ? el2.w : el2.z)                   \
                               : ((sym & 1) ? el2.y : el2.x);                  \
    const float nM1 = e1 * fmaf(tdm0, nbD, fmaf(tim0, nbI, tmm0 * nbM));       \
    const float nM2 = e2 * fmaf(tdm1, cD1, fmaf(tim1, cI1, tmm1 * cM1));       \
    const float nI1 = fmaf(tmi1, cM1, tii1 * cI1);  /* 0.25 folded */          \
    const float nI2 = fmaf(tmi2, cM2, tii2 * cI2);                             \
    const float nD1 = fmaf(tmd0, qM, tdd0 * qD);                               \
    const float nD2 = fmaf(tmd1, nM1, tdd1 * nD1);                             \
    fI0 = isS1 ? q1g : gg * fI0;                                               \
    if ((MODE) == 1) {                                                         \
        cM1 = nM1; cM2 = nM2; cI1 = nI1; cI2 = nI2; cD1 = nD1; cD2 = nD2;      \
    } else if ((MODE) == 0) {                                                  \
        const int c = (S) - i;                                                 \
        const bool act = (c >= 1), actD = (c >= 0);                            \
        cM1 = act  ? nM1 : cM1; cM2 = act  ? nM2 : cM2;                        \
        cI1 = act  ? nI1 : cI1; cI2 = act  ? nI2 : cI2;                        \
        cD1 = actD ? nD1 : cD1; cD2 = actD ? nD2 : cD2;                        \
    } else {                                                                   \
        const int c = (S) - i;                                                 \
        const bool act = (c <= 256);                                           \
        cM1 = act ? nM1 : cM1; cM2 = act ? nM2 : cM2;                          \
        cI1 = act ? nI1 : cI1; cI2 = act ? nI2 : cI2;                          \
        cD1 = act ? nD1 : cD1; cD2 = act ? nD2 : cD2;                          \
    }                                                                          \
    pM = qM; pI = qI; pD = qD;                                                 \
} while (0)

// Renormalize own scale every 4-step group (exact: pure power-of-2 shifts).
#define RESCALE do {                                                           \
    const float anc = fmaxf(fmaxf(fmaxf(cM1, cM2), fmaxf(cI1, cI2)),           \
                            fmaxf(cD1, cD2));                                  \
    const int e = fxe(anc);                                                    \
    E += e;                                                                    \
    cM1 = ldx(cM1, -e); cM2 = ldx(cM2, -e);                                    \
    cI1 = ldx(cI1, -e); cI2 = ldx(cI2, -e);                                    \
    cD1 = ldx(cD1, -e); cD2 = ldx(cD2, -e);                                    \
    pM  = ldx(pM,  -e); pI  = ldx(pI,  -e); pD = ldx(pD, -e);                  \
    const int eI = fxe(fI0); EI0 += eI; fI0 = ldx(fI0, -eI);                   \
} while (0)

// transitions: (B, 129, 7)  M2M=0 M2I=1 M2D=2 I2M=3 I2I=4 D2M=5 D2D=6
// emissions:   (B, 128, 4);  tokens: (B, 256) int32 in [0,4)
__global__ __launch_bounds__(64) void phmm_fwd(const int* __restrict__ tokens,
                                               const float* __restrict__ trans,
                                               const float* __restrict__ emis,
                                               float* __restrict__ nll_out)
{
    const int b = blockIdx.x;
    const int i = threadIdx.x;
    const bool lane0 = (i == 0);

    const float* ab = trans + (size_t)b * 903;
    const int r0 = (2 * i) * 7, r1 = (2 * i + 1) * 7, r2 = (2 * i + 2) * 7;

    // Linear-space params (exp of the raw log-params) — 25 trans ops at INIT.
    const float tmm0 = exp2_hw(ab[r0 + 0] * LOG2E);
    const float tim0 = exp2_hw(ab[r0 + 3] * LOG2E);
    const float tdm0 = exp2_hw(ab[r0 + 5] * LOG2E);
    const float tmd0 = exp2_hw(ab[r0 + 2] * LOG2E);
    const float tdd0 = exp2_hw(ab[r0 + 6] * LOG2E);
    const float tmm1 = exp2_hw(ab[r1 + 0] * LOG2E);
    const float tim1 = exp2_hw(ab[r1 + 3] * LOG2E);
    const float tdm1 = exp2_hw(ab[r1 + 5] * LOG2E);
    const float tmd1 = exp2_hw(ab[r1 + 2] * LOG2E);
    const float tdd1 = exp2_hw(ab[r1 + 6] * LOG2E);
    const float tmi1 = 0.25f * exp2_hw(ab[r1 + 1] * LOG2E); // LOG(1/4) folded
    const float tii1 = 0.25f * exp2_hw(ab[r1 + 4] * LOG2E);
    const float tmi2 = 0.25f * exp2_hw(ab[r2 + 1] * LOG2E);
    const float tii2 = 0.25f * exp2_hw(ab[r2 + 4] * LOG2E);
    const float q1g  = 0.25f * exp2_hw(ab[1] * LOG2E);      // fI0[1] seed
    const float gg   = 0.25f * exp2_hw(ab[4] * LOG2E);      // fI0 geometric link
    const float tKmm = exp2_hw(ab[128 * 7 + 0] * LOG2E);
    const float tKim = exp2_hw(ab[128 * 7 + 3] * LOG2E);
    const float tKdm = exp2_hw(ab[128 * 7 + 5] * LOG2E);

    const float4* eb = (const float4*)(emis + (size_t)b * 512);
    float4 el1 = eb[2 * i];
    float4 el2 = eb[2 * i + 1];
    el1.x = exp2_hw(el1.x * LOG2E); el1.y = exp2_hw(el1.y * LOG2E);
    el1.z = exp2_hw(el1.z * LOG2E); el1.w = exp2_hw(el1.w * LOG2E);
    el2.x = exp2_hw(el2.x * LOG2E); el2.y = exp2_hw(el2.y * LOG2E);
    el2.z = exp2_hw(el2.z * LOG2E); el2.w = exp2_hw(el2.w * LOG2E);

    const int4 tok_store = ((const int4*)(tokens + (size_t)b * 256))[i];

    // Linear state (own scale 2^E). "Impossible" (log -100) == exact 0.
    float cM1 = 0.0f, cM2 = 0.0f, cI1 = 0.0f, cI2 = 0.0f;
    float pM = lane0 ? 1.0f : 0.0f;   // fM[0][0] = 1 seeds step 1
    float pI = 0.0f, pD = 0.0f;
    float fI0 = 0.0f;                 // fI[0][c-1], wave-uniform, scale 2^EI0
    // lane 0's column-0 delete chain: fD[1][0]=tmd0, fD[2][0]=tdd1*tmd0
    float cD1 = lane0 ? tmd0 : 0.0f;
    float cD2 = lane0 ? tdd1 * tmd0 : 0.0f;
    int E = 0, EI0 = 0;
    int tok = 0;

    // steps s = 1 .. 320; lane i active for s in [i+1, i+256]; D-init at s == i.
    #pragma unroll 1
    for (int u = 0; u < 16; ++u) {          // s in [1,64]: fill
        const int f0 = __builtin_amdgcn_readlane(tok_store.x, u);
        const int f1 = __builtin_amdgcn_readlane(tok_store.y, u);
        const int f2 = __builtin_amdgcn_readlane(tok_store.z, u);
        const int f3 = __builtin_amdgcn_readlane(tok_store.w, u);
        const int s0 = 1 + 4 * u;
        STEP(s0 + 0, f0, 0); STEP(s0 + 1, f1, 0);
        STEP(s0 + 2, f2, 0); STEP(s0 + 3, f3, 0);
        RESCALE;
    }
    #pragma unroll 1
    for (int u = 16; u < 64; ++u) {         // s in [65,256]: steady, all active
        const int f0 = __builtin_amdgcn_readlane(tok_store.x, u);
        const int f1 = __builtin_amdgcn_readlane(tok_store.y, u);
        const int f2 = __builtin_amdgcn_readlane(tok_store.z, u);
        const int f3 = __builtin_amdgcn_readlane(tok_store.w, u);
        const int s0 = 1 + 4 * u;
        STEP(s0 + 0, f0, 1); STEP(s0 + 1, f1, 1);
        STEP(s0 + 2, f2, 1); STEP(s0 + 3, f3, 1);
        RESCALE;
    }
    #pragma unroll 1
    for (int u = 64; u < 80; ++u) {         // s in [257,320]: drain
        const int s0 = 1 + 4 * u;
        STEP(s0 + 0, 0, 2); STEP(s0 + 1, 0, 2);
        STEP(s0 + 2, 0, 2); STEP(s0 + 3, 0, 2);
        RESCALE;
    }

    // lane 63 holds k=128 @ col 256 in (cM2,cI2,cD2), scale 2^E.
    const float fin = fmaf(tKdm, cD2, fmaf(tKim, cI2, tKmm * cM2));
    if (i == 63) nll_out[b] = -(log2_hw(fin) + (float)E) * LN2;
}

__global__ __launch_bounds__(256) void phmm_finish(const float* __restrict__ nll,
                                                   const float* __restrict__ mus,
                                                   const float* __restrict__ logvars,
                                                   float* __restrict__ out)
{
    const int tid = threadIdx.x;
    float acc = 0.0f;
    for (int idx = tid; idx < 512; idx += 256) acc += nll[idx];
    for (int idx = tid; idx < 8192; idx += 256) {
        const float mu = mus[idx], lv = logvars[idx];
        acc -= 0.5f * (1.0f + lv - mu * mu - exp2_hw(lv * LOG2E));
    }
    #pragma unroll
    for (int off = 32; off >= 1; off >>= 1) acc += __shfl_down(acc, off);
    __shared__ float red[4];
    if ((tid & 63) == 0) red[tid >> 6] = acc;
    __syncthreads();
    if (tid == 0) out[0] = (red[0] + red[1] + red[2] + red[3]) * (1.0f / 512.0f);
}

extern "C" void kernel_launch(void* const* d_in, const int* in_sizes, int n_in,
                              void* d_out, int out_size, void* d_ws, size_t ws_size,
                              hipStream_t stream)
{
    const int*   tokens  = (const int*)d_in[0];   // (512, 256) int32
    const float* trans   = (const float*)d_in[1]; // (512, 129, 7) f32
    const float* emis    = (const float*)d_in[2]; // (512, 128, 4) f32
    const float* mus     = (const float*)d_in[3]; // (512, 16) f32
    const float* logvars = (const float*)d_in[4]; // (512, 16) f32
    float* nll = (float*)d_ws;                    // 512 floats scratch

    phmm_fwd<<<dim3(512), dim3(64), 0, stream>>>(tokens, trans, emis, nll);
    phmm_finish<<<dim3(1), dim3(256), 0, stream>>>(nll, mus, logvars, (float*)d_out);
}